// Round 11
// baseline (258.517 us; speedup 1.0000x reference)
//
#include <hip/hip_runtime.h>
#include <math.h>

// RBFController: B=2048, N=32 centers, D=64 dims, A=8 actions.
// One 256-thread block per batch element. R11: latency-bound at 3 waves/SIMD
// (R8/R10 LDS-cut rounds were neutral -> LDS-pipe model falsified). Joint
// LDS+VGPR diet for 4 blocks/CU:
//  - LDS 53760 -> 40832 B: H aliases LmT2 rows 0..31 (wave1 is the only
//    phase-S LmT2 reader; its H writes are data-dependent on all its reads);
//    diag/invd/am/Ca/acr/ldlh live in LmT pad words 64..67 (solves read
//    words 0..63 only); cp_s held in wave0 registers; l2h recomputed.
//  - __launch_bounds__(256,4): VGPR cap 64 (live set ~55-60 in hot phases).
// All FP sequences bitwise identical to R10 (absmax must stay 1.490116e-08).
// Pad-slot map: LmT*[r*STR+64]=diag, +65=invd; LmT1[r*STR+66]=acr[r] (r<64),
// LmT1[0*STR+67]=ldlh; LmT2[a*STR+66]=Ca[a], +67=am[a] (a<8).

#define DD 64
#define NN 32
#define AA 8
#define NBATCH 2048
#define STR 68   // L^T row stride (words): 64 data + 4 pad, 16B-aligned rows
#define W9 9     // padded stride for w9_s / K_s (kills 8-way bank conflicts)

// ---------------- prep: exp1[n][m] table + logdet_lh scalar ----------------
__global__ void rbf_prep(const float* __restrict__ centers,
                         const float* __restrict__ ls,
                         float* __restrict__ ws) {
    __shared__ float cen_s[NN * DD];
    __shared__ float il2_s[DD];
    int t = threadIdx.x;
    for (int e = t; e < NN * DD; e += 256) cen_s[e] = centers[e];
    if (t < DD) { float l = ls[t]; il2_s[t] = 1.0f / (l * l); }
    __syncthreads();
    int p = blockIdx.x * 256 + t;
    if (p < NN * NN) {
        int n = p >> 5, m = p & 31;
        float acc = 0.f;
        for (int d = 0; d < DD; ++d) {
            float df = cen_s[n * DD + d] - cen_s[m * DD + d];
            acc += df * df * il2_s[d];
        }
        ws[p] = -0.25f * acc;              // exp1[n][m]
    }
    if (blockIdx.x == 0 && t < DD) {
        float l = ls[t];
        float v = logf(0.5f * l * l);
        #pragma unroll
        for (int o = 1; o < 64; o <<= 1) v += __shfl_xor(v, o, 64);
        if (t == 0) ws[NN * NN] = v;       // logdet_lh
    }
}

// Wave-local panel factorization (PROVEN shfl version). PRECONDITION:
// executing wave owns cols 16p..16p+15 of A (lane lw: rows 4*(lw&15)..,
// panel-local col tile lw>>4). diag/invd written to LmT pad words 64/65.
__device__ __forceinline__ void factor_panel(float (&A)[4][4], const int p,
    float* __restrict__ LmT, const int lw)
{
    const int rb  = lw & 15;
    const int cbl = lw >> 4;
    const int c0  = 16 * p + 4 * cbl;
    const int r0  = 4 * rb;
    #pragma unroll
    for (int jj = 0; jj < 16; ++jj) {
        const int q  = jj >> 2;
        const int ci = jj & 3;
        const int j  = 16 * p + jj;
        const int fsrc = rb | (q << 4);
        const int hsrc = (4 * p + cbl) | (q << 4);
        const int dsrc = (4 * p + q) | (q << 4);
        float d  = __shfl(A[ci][ci], dsrc, 64);
        float f0 = __shfl(A[0][ci], fsrc, 64);
        float f1 = __shfl(A[1][ci], fsrc, 64);
        float f2 = __shfl(A[2][ci], fsrc, 64);
        float f3 = __shfl(A[3][ci], fsrc, 64);
        float h0 = __shfl(A[0][ci], hsrc, 64);
        float h1 = __shfl(A[1][ci], hsrc, 64);
        float h2 = __shfl(A[2][ci], hsrc, 64);
        float h3 = __shfl(A[3][ci], hsrc, 64);
        float id = __builtin_amdgcn_rcpf(d);   // cond(A) ~ 1; ~1ulp fine
        float fr[4];
        fr[0] = (r0 + 0 > j) ? f0 : 0.f;
        fr[1] = (r0 + 1 > j) ? f1 : 0.f;
        fr[2] = (r0 + 2 > j) ? f2 : 0.f;
        fr[3] = (r0 + 3 > j) ? f3 : 0.f;
        float hc[4];
        hc[0] = (c0 + 0 > j) ? h0 * id : 0.f;
        hc[1] = (c0 + 1 > j) ? h1 * id : 0.f;
        hc[2] = (c0 + 2 > j) ? h2 * id : 0.f;
        hc[3] = (c0 + 3 > j) ? h3 * id : 0.f;
        #pragma unroll
        for (int s = 0; s < 4; ++s)
            #pragma unroll
            for (int c = 0; c < 4; ++c)
                A[s][c] -= fr[s] * hc[c];
        if (cbl == 0) {
            float4 v = make_float4(fr[0] * id, fr[1] * id, fr[2] * id, fr[3] * id);
            *(float4*)&LmT[j * STR + r0] = v;
        }
        if (lw == jj) { LmT[j * STR + 64] = d; LmT[j * STR + 65] = id; }
    }
}

// Rank-16 trailing update, single matrix. Zero-filled L^T rows auto-mask <=k.
__device__ __forceinline__ void trailing_one(float (&A)[4][4], const int p,
    const float* __restrict__ LmT, const int rb, const int cbX)
{
    #pragma unroll 2
    for (int kk = 0; kk < 16; ++kk) {
        const int k = 16 * p + kk;
        const float4 Lr = *(const float4*)&LmT[k * STR + 4 * rb];
        const float4 Lc = *(const float4*)&LmT[k * STR + 4 * cbX];
        const float dk = LmT[k * STR + 64];
        const float h0 = Lc.x * dk, h1 = Lc.y * dk, h2 = Lc.z * dk, h3 = Lc.w * dk;
        A[0][0] -= Lr.x * h0; A[0][1] -= Lr.x * h1; A[0][2] -= Lr.x * h2; A[0][3] -= Lr.x * h3;
        A[1][0] -= Lr.y * h0; A[1][1] -= Lr.y * h1; A[1][2] -= Lr.y * h2; A[1][3] -= Lr.y * h3;
        A[2][0] -= Lr.z * h0; A[2][1] -= Lr.z * h1; A[2][2] -= Lr.z * h2; A[2][3] -= Lr.z * h3;
        A[3][0] -= Lr.w * h0; A[3][1] -= Lr.w * h1; A[3][2] -= Lr.w * h2; A[3][3] -= Lr.w * h3;
    }
}

__global__ __launch_bounds__(256, 4) void rbf_main(
    const float* __restrict__ mean,      // (B,64)
    const float* __restrict__ cov,       // (B,64,64)
    const float* __restrict__ centers,   // (32,64)
    const float* __restrict__ weights,   // (32,8)
    const float* __restrict__ ls,        // (64,)
    const float* __restrict__ ws,        // exp1[1024], logdet_lh at [1024]
    float* __restrict__ out)
{
    __shared__ __align__(16) float LmT1[DD * STR];  // 17408 B  L1^T + pads
    __shared__ __align__(16) float LmT2[DD * STR];  // 17408 B  L2^T + pads; rows 0..31 words 0..63 = H after phase S
    __shared__ __align__(16) float K_s[DD * W9];    // 2304 B
    __shared__ __align__(16) float w9_s[NN * W9];   // 1152 B
    __shared__ __align__(16) float phiwc[NN * AA];  // 1024 B
    __shared__ __align__(16) float U_s[NN * AA];    // 1024 B
    __shared__ __align__(16) float mean_s[DD];      // 256 B
    __shared__ __align__(16) float invl_s[DD];      // 256 B
    // total 40832 B -> 4 blocks/CU (4 x 40960 = 163840 exactly)

    const int t   = threadIdx.x;
    const int b   = blockIdx.x;
    const int lw  = t & 63;
    const int wv  = t >> 6;
    const int rb  = t & 15;            // row tile (rows 4rb..4rb+3), both matrices
    const int cb  = t >> 4;            // M2 col tile; wave w owns M2 cols 16w..16w+15
    const int cb1 = (cb + 8) & 15;     // M1 col tile; wave w owns M1 panel (w+2)&3
    const int wp1 = (wv + 2) & 3;      // M1 panel owned by this wave
    const int l8  = t & 7;             // lane-in-group (rows 8*l8..8*l8+7)
    const float* cvb = cov + (size_t)b * DD * DD;

    // ---- stage small arrays ----
    if (t < DD) {
        float l = ls[t];
        invl_s[t] = 1.0f / l;
        mean_s[t] = mean[(size_t)b * DD + t];
    }
    w9_s[(t >> 3) * W9 + (t & 7)] = weights[t];
    if (t == 0) LmT1[0 * STR + 67] = ws[NN * NN];   // ldlh
    __syncthreads();

    // ---- build tiles: A2 at (4rb, 4cb), A1 at (4rb, 4cb1) — symmetric loads
    float A1[4][4], A2[4][4];
    {
        #pragma unroll
        for (int c = 0; c < 4; ++c) {
            const int gr = 4 * cb + c;
            const float4 cv = *(const float4*)(cvb + (size_t)gr * DD + 4 * rb);
            const float lg = ls[gr];
            const float l2h = 0.5f * lg * lg;   // same expression as before: bitwise id
            A2[0][c] = cv.x + ((4*rb+0 == gr) ? l2h : 0.0f);
            A2[1][c] = cv.y + ((4*rb+1 == gr) ? l2h : 0.0f);
            A2[2][c] = cv.z + ((4*rb+2 == gr) ? l2h : 0.0f);
            A2[3][c] = cv.w + ((4*rb+3 == gr) ? l2h : 0.0f);
        }
        const float il0 = invl_s[4*rb+0], il1 = invl_s[4*rb+1],
                    il2 = invl_s[4*rb+2], il3 = invl_s[4*rb+3];
        #pragma unroll
        for (int c = 0; c < 4; ++c) {
            const int gr = 4 * cb1 + c;
            const float4 cv = *(const float4*)(cvb + (size_t)gr * DD + 4 * rb);
            const float ilc = invl_s[gr];
            A1[0][c] = cv.x * il0 * ilc + ((4*rb+0 == gr) ? 1.0f : 0.0f);
            A1[1][c] = cv.y * il1 * ilc + ((4*rb+1 == gr) ? 1.0f : 0.0f);
            A1[2][c] = cv.z * il2 * ilc + ((4*rb+2 == gr) ? 1.0f : 0.0f);
            A1[3][c] = cv.w * il3 * ilc + ((4*rb+3 == gr) ? 1.0f : 0.0f);
        }
    }

    // ---- FUSED factorization with wave-uniform trailing skip ----
    if (wv == 0) factor_panel(A2, 0, LmT2, lw);
    if (wv == 2) factor_panel(A1, 0, LmT1, lw);
    #pragma unroll 1
    for (int p = 0; p < 3; ++p) {
        __syncthreads();
        if (wv  >= p + 1) trailing_one(A2, p, LmT2, rb, cb);
        if (wp1 >= p + 1) trailing_one(A1, p, LmT1, rb, cb1);
        if (wv == p + 1)         factor_panel(A2, p + 1, LmT2, lw);
        if (wv == ((p + 3) & 3)) factor_panel(A1, p + 1, LmT1, lw);
    }
    __syncthreads();

    // ---- per-wave logdets (redundant; no barrier needed) ----
    float logdet1, cq;
    {
        float v1 = logf(LmT1[lw * STR + 64]);
        float v2 = logf(LmT2[lw * STR + 64]);
        #pragma unroll
        for (int o = 1; o < 64; o <<= 1) {
            v1 += __shfl_xor(v1, o, 64);
            v2 += __shfl_xor(v2, o, 64);
        }
        logdet1 = v1;
        cq = expf(0.5f * (LmT1[0 * STR + 67] - v2));
    }

    // ---- phase S: wave0 = M1 solve (32 RHS, 4/lane); wave1 = M2 solve ----
    // L rows read ONCE per matrix; wave1 writes H over LmT2 rows 0..31
    // (words 0..63) AFTER its own last LmT2 read — no other wave reads LmT2.
    if (wv == 0) {
        const int gr8 = lw >> 3;   // RHS n = gr8 + 8*rr
        float x0[8], x1v[8], x2v[8], x3v[8];
        #pragma unroll
        for (int rr = 0; rr < 4; ++rr) {
            const int n = gr8 + 8 * rr;
            const float4 ca = *(const float4*)(centers + n * DD + 8 * l8);
            const float4 cz = *(const float4*)(centers + n * DD + 8 * l8 + 4);
            float da[8] = {ca.x,ca.y,ca.z,ca.w,cz.x,cz.y,cz.z,cz.w};
            float* xp = (rr == 0) ? x0 : (rr == 1) ? x1v : (rr == 2) ? x2v : x3v;
            #pragma unroll
            for (int s = 0; s < 8; ++s) {
                const int i = 8 * l8 + s;
                xp[s] = (da[s] - mean_s[i]) * invl_s[i];
            }
        }
        for (int k8 = 0; k8 < 8; ++k8) {
            #pragma unroll
            for (int kk = 0; kk < 8; ++kk) {
                const int k = 8 * k8 + kk;
                const int src = (lw & 56) | k8;
                float z0 = __shfl(x0[kk],  src, 64);
                float z1 = __shfl(x1v[kk], src, 64);
                float z2 = __shfl(x2v[kk], src, 64);
                float z3 = __shfl(x3v[kk], src, 64);
                const float4 LA = *(const float4*)&LmT1[k * STR + 8 * l8];
                const float4 LB = *(const float4*)&LmT1[k * STR + 8 * l8 + 4];
                float l1[8] = {LA.x,LA.y,LA.z,LA.w,LB.x,LB.y,LB.z,LB.w};
                #pragma unroll
                for (int s = 0; s < 8; ++s) {
                    x0[s]  -= l1[s] * z0;
                    x1v[s] -= l1[s] * z1;
                    x2v[s] -= l1[s] * z2;
                    x3v[s] -= l1[s] * z3;
                }
            }
        }
        #pragma unroll
        for (int rr = 0; rr < 4; ++rr) {
            const int n = gr8 + 8 * rr;
            const float* xp = (rr == 0) ? x0 : (rr == 1) ? x1v : (rr == 2) ? x2v : x3v;
            float qf = 0.f;
            #pragma unroll
            for (int s = 0; s < 8; ++s) qf += xp[s] * xp[s] * LmT1[(8 * l8 + s) * STR + 65];
            qf += __shfl_xor(qf, 1, 64);
            qf += __shfl_xor(qf, 2, 64);
            qf += __shfl_xor(qf, 4, 64);
            float ph = expf(-0.5f * (logdet1 + qf));
            phiwc[n * AA + l8] = ph * w9_s[n * W9 + l8];
        }
    } else if (wv == 1) {
        const int gr8 = lw >> 3;
        float x0[8], x1v[8], x2v[8], x3v[8];
        #pragma unroll
        for (int rr = 0; rr < 4; ++rr) {
            const int n = gr8 + 8 * rr;
            const float4 ca = *(const float4*)(centers + n * DD + 8 * l8);
            const float4 cz = *(const float4*)(centers + n * DD + 8 * l8 + 4);
            float da[8] = {ca.x,ca.y,ca.z,ca.w,cz.x,cz.y,cz.z,cz.w};
            float* xp = (rr == 0) ? x0 : (rr == 1) ? x1v : (rr == 2) ? x2v : x3v;
            #pragma unroll
            for (int s = 0; s < 8; ++s) {
                const int i = 8 * l8 + s;
                xp[s] = 0.5f * (da[s] - mean_s[i]);
            }
        }
        for (int k8 = 0; k8 < 8; ++k8) {
            #pragma unroll
            for (int kk = 0; kk < 8; ++kk) {
                const int k = 8 * k8 + kk;
                const int src = (lw & 56) | k8;
                float z0 = __shfl(x0[kk],  src, 64);
                float z1 = __shfl(x1v[kk], src, 64);
                float z2 = __shfl(x2v[kk], src, 64);
                float z3 = __shfl(x3v[kk], src, 64);
                const float4 MA = *(const float4*)&LmT2[k * STR + 8 * l8];
                const float4 MB = *(const float4*)&LmT2[k * STR + 8 * l8 + 4];
                float l2[8] = {MA.x,MA.y,MA.z,MA.w,MB.x,MB.y,MB.z,MB.w};
                #pragma unroll
                for (int s = 0; s < 8; ++s) {
                    x0[s]  -= l2[s] * z0;
                    x1v[s] -= l2[s] * z1;
                    x2v[s] -= l2[s] * z2;
                    x3v[s] -= l2[s] * z3;
                }
            }
        }
        #pragma unroll
        for (int rr = 0; rr < 4; ++rr) {
            const int n = gr8 + 8 * rr;
            const float* xp = (rr == 0) ? x0 : (rr == 1) ? x1v : (rr == 2) ? x2v : x3v;
            float h[8];
            #pragma unroll
            for (int s = 0; s < 8; ++s) h[s] = xp[s] * sqrtf(LmT2[(8 * l8 + s) * STR + 65]);
            *(float4*)&LmT2[n * STR + 8 * l8]     = make_float4(h[0],h[1],h[2],h[3]);  // H alias
            *(float4*)&LmT2[n * STR + 8 * l8 + 4] = make_float4(h[4],h[5],h[6],h[7]);
        }
    }
    __syncthreads();

    // ---- phase T: wave0 K-build + cp-solve | waves1,2 Gram pairs | wave3 amean
    float cpv[8];   // wave0: cp values held in registers to final write
    const int aa = lw >> 3;
    if (wv == 0) {
        {   // K[d][a] = sum_n s_n[d] * phiw[n][a]; d = lane, all 8 a
            const int d = lw;
            const float md = mean_s[d], il = invl_s[d];
            float k0=0.f,k1=0.f,k2=0.f,k3=0.f,k4=0.f,k5=0.f,k6=0.f,k7=0.f;
            for (int n = 0; n < NN; ++n) {
                const float sv = (centers[n * DD + d] - md) * il;
                const float4 pa = *(const float4*)&phiwc[n * AA];
                const float4 pb = *(const float4*)&phiwc[n * AA + 4];
                k0 += sv * pa.x; k1 += sv * pa.y; k2 += sv * pa.z; k3 += sv * pa.w;
                k4 += sv * pb.x; k5 += sv * pb.y; k6 += sv * pb.z; k7 += sv * pb.w;
            }
            K_s[d*W9+0]=k0; K_s[d*W9+1]=k1; K_s[d*W9+2]=k2; K_s[d*W9+3]=k3;
            K_s[d*W9+4]=k4; K_s[d*W9+5]=k5; K_s[d*W9+6]=k6; K_s[d*W9+7]=k7;
        }
        // cp-solve: 8 RHS, intra-wave dep on K_s
        float y[8];
        #pragma unroll
        for (int s = 0; s < 8; ++s) y[s] = K_s[(8 * l8 + s) * W9 + aa];
        for (int k8 = 0; k8 < 8; ++k8) {              // forward (unit-L)
            #pragma unroll
            for (int kk = 0; kk < 8; ++kk) {
                const int k = 8 * k8 + kk;
                float zk = __shfl(y[kk], (lw & 56) | k8, 64);
                #pragma unroll
                for (int s = 0; s < 8; ++s)
                    y[s] -= LmT1[k * STR + 8 * l8 + s] * zk;
            }
        }
        #pragma unroll
        for (int s = 0; s < 8; ++s) y[s] *= LmT1[(8 * l8 + s) * STR + 65];
        for (int i8 = 7; i8 >= 0; --i8) {             // backward (L^T), dot-form
            #pragma unroll
            for (int ii = 7; ii >= 0; --ii) {
                const int i = 8 * i8 + ii;
                const float4 r0 = *(const float4*)&LmT1[i * STR + 8 * l8];
                const float4 r1 = *(const float4*)&LmT1[i * STR + 8 * l8 + 4];
                float part = r0.x*y[0] + r0.y*y[1] + r0.z*y[2] + r0.w*y[3]
                           + r1.x*y[4] + r1.y*y[5] + r1.z*y[6] + r1.w*y[7];
                part += __shfl_xor(part, 1, 64);
                part += __shfl_xor(part, 2, 64);
                part += __shfl_xor(part, 4, 64);
                if (l8 == i8) y[ii] -= part;
            }
        }
        #pragma unroll
        for (int s = 0; s < 8; ++s)
            cpv[s] = y[s] * invl_s[8 * l8 + s];
    } else if (wv == 3) {
        if (lw < AA) {
            const int a = lw;
            float am = 0.f;
            for (int n = 0; n < NN; ++n) am += phiwc[n * AA + a];
            LmT2[a * STR + 67] = am;   // am pad slot
        }
    } else {
        // Gram pairs: 16 groups (waves 1,2) x 2 rows (n0=g, n1=g+16); H = LmT2 rows
        const int g16 = (lw >> 3) + 8 * (wv - 1);
        const int n0 = g16, n1 = g16 + 16;
        float acc0[4] = {0.f,0.f,0.f,0.f}, acc1[4] = {0.f,0.f,0.f,0.f};
        const int rot = 2 * l8;
        #pragma unroll 2
        for (int e = 0; e < 16; ++e) {
            const int e4 = 4 * ((e + rot) & 15);
            const float4 hn0 = *(const float4*)&LmT2[n0 * STR + e4];
            const float4 hn1 = *(const float4*)&LmT2[n1 * STR + e4];
            #pragma unroll
            for (int mm = 0; mm < 4; ++mm) {
                const float4 hm = *(const float4*)&LmT2[(4 * l8 + mm) * STR + e4];
                {
                    float s0 = hn0.x + hm.x, s1 = hn0.y + hm.y;
                    float s2 = hn0.z + hm.z, s3 = hn0.w + hm.w;
                    acc0[mm] += s0*s0 + s1*s1 + s2*s2 + s3*s3;
                }
                {
                    float s0 = hn1.x + hm.x, s1 = hn1.y + hm.y;
                    float s2 = hn1.z + hm.z, s3 = hn1.w + hm.w;
                    acc1[mm] += s0*s0 + s1*s1 + s2*s2 + s3*s3;
                }
            }
        }
        const float4 e1a = *(const float4*)&ws[n0 * NN + 4 * l8];
        const float4 e1b = *(const float4*)&ws[n1 * NN + 4 * l8];
        float Q0a = cq * expf(e1a.x - 0.5f * acc0[0]);
        float Q1a = cq * expf(e1a.y - 0.5f * acc0[1]);
        float Q2a = cq * expf(e1a.z - 0.5f * acc0[2]);
        float Q3a = cq * expf(e1a.w - 0.5f * acc0[3]);
        float Q0b = cq * expf(e1b.x - 0.5f * acc1[0]);
        float Q1b = cq * expf(e1b.y - 0.5f * acc1[1]);
        float Q2b = cq * expf(e1b.z - 0.5f * acc1[2]);
        float Q3b = cq * expf(e1b.w - 0.5f * acc1[3]);
        float ua[8], ub[8];
        #pragma unroll
        for (int a = 0; a < 8; ++a) {
            const float w0 = w9_s[(4*l8+0)*W9 + a], w1 = w9_s[(4*l8+1)*W9 + a];
            const float w2 = w9_s[(4*l8+2)*W9 + a], w3 = w9_s[(4*l8+3)*W9 + a];
            ua[a] = Q0a*w0 + Q1a*w1 + Q2a*w2 + Q3a*w3;
            ub[a] = Q0b*w0 + Q1b*w1 + Q2b*w2 + Q3b*w3;
            ua[a] += __shfl_xor(ua[a], 1, 64);
            ua[a] += __shfl_xor(ua[a], 2, 64);
            ua[a] += __shfl_xor(ua[a], 4, 64);
            ub[a] += __shfl_xor(ub[a], 1, 64);
            ub[a] += __shfl_xor(ub[a], 2, 64);
            ub[a] += __shfl_xor(ub[a], 4, 64);
        }
        float uva = (l8 == 0) ? ua[0] : (l8 == 1) ? ua[1] : (l8 == 2) ? ua[2] : (l8 == 3) ? ua[3]
                  : (l8 == 4) ? ua[4] : (l8 == 5) ? ua[5] : (l8 == 6) ? ua[6] : ua[7];
        float uvb = (l8 == 0) ? ub[0] : (l8 == 1) ? ub[1] : (l8 == 2) ? ub[2] : (l8 == 3) ? ub[3]
                  : (l8 == 4) ? ub[4] : (l8 == 5) ? ub[5] : (l8 == 6) ? ub[6] : ub[7];
        U_s[n0 * AA + l8] = uva;
        U_s[n1 * AA + l8] = uvb;
    }
    __syncthreads();

    // ---- phase C: acr = w^T U  (stored in LmT1 pad word 66, row a*8+c) ----
    if (t < 64) {
        const int a = t >> 3, c = t & 7;
        float acc2 = 0.f;
        for (int n = 0; n < NN; ++n) acc2 += w9_s[n * W9 + a] * U_s[n * AA + c];
        LmT1[t * STR + 66] = acc2;
    }
    __syncthreads();

    // ---- squash + outputs ----
    float* out0 = out;
    float* out1 = out + (size_t)NBATCH * AA;
    float* out2 = out + (size_t)NBATCH * AA + (size_t)NBATCH * AA * AA;
    if (t < 64) {
        const int a = t >> 3, c = t & 7;
        const float ama = LmT2[a * STR + 67], amc = LmT2[c * STR + 67];
        const float vac = 0.5f * (LmT1[(a * 8 + c) * STR + 66] + LmT1[(c * 8 + a) * STR + 66])
                        - ama * amc + ((a == c) ? 1e-6f : 0.0f);
        const float dca = LmT1[(a * 8 + a) * STR + 66] - ama * ama + 1e-6f;
        const float dcc = LmT1[(c * 8 + c) * STR + 66] - amc * amc + 1e-6f;
        const float q = expf(-0.5f * (dca + dcc));
        // expm1 formulation avoids catastrophic cancellation at vac ~ 1e-6
        const float sq = 0.5f * q * (expm1f(vac) * cosf(ama - amc)
                                   - expm1f(-vac) * cosf(ama + amc));
        out1[(size_t)b * 64 + t] = sq;
        if (t < AA) {
            float amt = LmT2[t * STR + 67];
            float dct = LmT1[(t * 8 + t) * STR + 66] - amt * amt + 1e-6f;
            float e = expf(-0.5f * dct);
            out0[(size_t)b * AA + t] = e * sinf(amt);
            LmT2[t * STR + 66] = e * cosf(amt);   // Ca pad slot
        }
    }
    __syncthreads();
    if (wv == 0) {
        const float cav = LmT2[aa * STR + 66];
        #pragma unroll
        for (int s = 0; s < 8; ++s)
            out2[(size_t)b * 512 + (8 * l8 + s) * 8 + aa] = cpv[s] * cav;
    }
}

extern "C" void kernel_launch(void* const* d_in, const int* in_sizes, int n_in,
                              void* d_out, int out_size, void* d_ws, size_t ws_size,
                              hipStream_t stream) {
    (void)in_sizes; (void)n_in; (void)out_size; (void)ws_size;
    const float* mean    = (const float*)d_in[0];
    const float* cov     = (const float*)d_in[1];
    const float* centers = (const float*)d_in[2];
    const float* weights = (const float*)d_in[3];
    const float* ls      = (const float*)d_in[4];
    float* ws = (float*)d_ws;
    float* o  = (float*)d_out;
    rbf_prep<<<4, 256, 0, stream>>>(centers, ls, ws);
    rbf_main<<<NBATCH, 256, 0, stream>>>(mean, cov, centers, weights, ls, ws, o);
}